// Round 16
// baseline (260.491 us; speedup 1.0000x reference)
//
#include <hip/hip_runtime.h>

#define LOG2E 1.44269504088896340736f

typedef __attribute__((ext_vector_type(8))) _Float16 half8;
typedef __attribute__((ext_vector_type(4))) _Float16 half4;
typedef __attribute__((ext_vector_type(4))) float f32x4;
typedef __attribute__((ext_vector_type(2))) float f32x2;
typedef __attribute__((ext_vector_type(2))) unsigned int uint2v;

constexpr int CL       = 8;               // layers per staged chunk (divides 1000)
constexpr int LAYER_BY = 1536;            // bytes/layer: 64 lanes x (16B A0 + 8B A1)
constexpr int CHUNK_BY = CL * LAYER_BY;   // 12288
constexpr int CHUNK_V4 = CHUNK_BY / 16;   // 768 float4
constexpr int V4_PER_T = CHUNK_V4 / 256;  // 3 per thread

// K=16 k-slot map (self-consistent between prepack/A and runtime/B):
//   chunk k0: slot(h,e) -> position 4h+e      (positions 0..15)
//   chunk k1: slot(h,e) -> position 16+4h+e   (16..19 real, 20 = bias, >20 pad)
// D layout (shape-determined, m89): col=lane&15, row=4*(lane>>4)+reg.

__device__ __forceinline__ unsigned short f16_rne(float f) {
    _Float16 h = (_Float16)f;   // RNE
    return __builtin_bit_cast(unsigned short, h);
}

// One block per layer; 64 threads (one per lane). Weights/bias PRE-SCALED by
// 0.5 (x = 0.5z feeds the Pade sigmoid directly), converted to f16.
__global__ void prepack(const float* __restrict__ W, const float* __restrict__ b,
                        unsigned int* __restrict__ wstream, int L)
{
    const int l    = blockIdx.x;
    const int lane = threadIdx.x;     // 0..63
    const int n    = lane & 15;       // tile0 neuron row
    const int h    = lane >> 4;

    unsigned short v[12];             // A0k0[4], A0k1[4], A1k1[4]
#pragma unroll
    for (int e = 0; e < 4; ++e) {
        // A0k0: W[n][4h+e], always real
        v[e] = f16_rne(0.5f * W[(size_t)l * 400 + n * 20 + (4 * h + e)]);
        // A0k1: pos 16+4h+e
        int p = 16 + 4 * h + e;
        float a = 0.f;
        if (p < 20)       a = 0.5f * W[(size_t)l * 400 + n * 20 + p];
        else if (p == 20) a = 0.5f * b[(size_t)l * 20 + n];
        v[4 + e] = f16_rne(a);
        // A1k1: tile1 neuron m1 = 16+n (real for n<4), same k1 slots
        float c = 0.f;
        int m1 = 16 + n;
        if (m1 < 20) {
            if (p < 20)       c = 0.5f * W[(size_t)l * 400 + m1 * 20 + p];
            else if (p == 20) c = 0.5f * b[(size_t)l * 20 + m1];
        }
        v[8 + e] = f16_rne(c);
    }
    unsigned w0 = (unsigned)v[0] | ((unsigned)v[1]  << 16);
    unsigned w1 = (unsigned)v[2] | ((unsigned)v[3]  << 16);
    unsigned w2 = (unsigned)v[4] | ((unsigned)v[5]  << 16);
    unsigned w3 = (unsigned)v[6] | ((unsigned)v[7]  << 16);
    unsigned w4 = (unsigned)v[8] | ((unsigned)v[9]  << 16);
    unsigned w5 = (unsigned)v[10]| ((unsigned)v[11] << 16);

    unsigned int* d0 = wstream + ((size_t)l * LAYER_BY + lane * 16) / 4;
    d0[0] = w0; d0[1] = w1; d0[2] = w2; d0[3] = w3;
    unsigned int* d1 = wstream + ((size_t)l * LAYER_BY + 1024 + lane * 8) / 4;
    d1[0] = w4; d1[1] = w5;
}

__device__ __forceinline__ unsigned pkrtz(float a, float b) {
    auto r = __builtin_amdgcn_cvt_pkrtz(a, b);   // __fp16 ext_vector(2)
    return __builtin_bit_cast(unsigned, r);
}
__device__ __forceinline__ half4 mk_half4(unsigned lo, unsigned hi) {
    uint2v u; u.x = lo; u.y = hi;
    return __builtin_bit_cast(half4, u);
}

__device__ __forceinline__ f32x2 make2(float v) { f32x2 r; r.x = v; r.y = v; return r; }

// sigmoid(z) with x = 0.5*z (scale folded into weights): 0.5 + x*N(u)/D(u).
// abs err <= ~2e-5 (|z|<=4), <= 1.2e-3 (z=8). Paired reciprocal: 1 rcp per 2
// divisions (rcp(dx*dy) * dy|dx) -> 4 rcp/layer instead of 8.
__device__ __forceinline__ f32x2 pade_sig(f32x2 x) {
    f32x2 u = x * x;
    f32x2 n = (u * make2(0.5f) + make2(52.5f)) * u + make2(472.5f);
    f32x2 d = (u * make2(15.0f) + make2(420.0f)) * u + make2(945.0f);
    float pr = __builtin_amdgcn_rcpf(d.x * d.y);
    f32x2 inv; inv.x = pr * d.y; inv.y = pr * d.x;
    return (x * n) * inv + make2(0.5f);
}

// full sigmoid for unscaled z (epilogue only, once)
__device__ __forceinline__ float sigm(float z) {
    return __builtin_amdgcn_rcpf(1.f + __builtin_amdgcn_exp2f(-LOG2E * z));
}

__device__ __forceinline__ void layer_step(const half8& a0, const half4& a1,
                                           half4& Bk0, half4& Bk1,
                                           f32x2 (&q)[4], int h) {
    const f32x4 z4 = {0.f, 0.f, 0.f, 0.f};
    const half4 A0k0 = __builtin_shufflevector(a0, a0, 0, 1, 2, 3);
    const half4 A0k1 = __builtin_shufflevector(a0, a0, 4, 5, 6, 7);
    // tile1 first: its D is on the loop-carried critical path (Bk1).
    f32x4 acc1 = __builtin_amdgcn_mfma_f32_16x16x16f16(a1,   Bk1, z4, 0, 0, 0);
    f32x4 acc0 = __builtin_amdgcn_mfma_f32_16x16x16f16(A0k0, Bk0, z4, 0, 0, 0);
    acc0       = __builtin_amdgcn_mfma_f32_16x16x16f16(A0k1, Bk1, acc0, 0, 0, 0);
    q[2].x = acc1[0]; q[2].y = acc1[1];
    q[3].x = acc1[2]; q[3].y = acc1[3];
    q[2] = pade_sig(q[2]); q[3] = pade_sig(q[3]);
    q[0].x = acc0[0]; q[0].y = acc0[1];
    q[1].x = acc0[2]; q[1].y = acc0[3];
    q[0] = pade_sig(q[0]); q[1] = pade_sig(q[1]);
    Bk0 = mk_half4(pkrtz(q[0].x, q[0].y), pkrtz(q[1].x, q[1].y));
    unsigned k1w0 = (h == 0) ? pkrtz(q[2].x, q[2].y)
                             : ((h == 1) ? 0x00003C00u : 0u);   // (1.0, 0) f16
    unsigned k1w1 = (h == 0) ? pkrtz(q[3].x, q[3].y) : 0u;
    Bk1 = mk_half4(k1w0, k1w1);
}

// Read one layer's fragments (b128 + b64), volatile so they cannot be sunk.
#define RD(OFF, A, Bv)                                                          \
    asm volatile("ds_read_b128 %0, %1 offset:" #OFF : "=v"(A)  : "v"(cb1));     \
    asm volatile("ds_read_b64 %0, %1 offset:" #OFF  : "=v"(Bv) : "v"(cb2));

// 16 batch rows per wave; 1024 waves = 1/SIMD (structural). Whole chunk's
// fragments (8 layers, 48 VGPRs) loaded up-front; the 8 layer_steps form ONE
// scheduling region (no per-layer waits/sched_barriers) so off-critical-path
// work (acc0 pade/pack) overlaps the next layer's critical Bk1 chain.
__global__ __launch_bounds__(256, 1) void mann_mfma(
    const float* __restrict__ x, const unsigned int* __restrict__ wstream,
    const float* __restrict__ Wout, const float* __restrict__ bout,
    float* __restrict__ out, int B, int L)
{
    __shared__ unsigned char lds[2 * CHUNK_BY];   // 24 KiB double buffer

    const int tid  = threadIdx.x;
    const int lane = tid & 63;
    const int c16  = lane & 15;
    const int h    = lane >> 4;
    const int w    = (blockIdx.x * 256 + tid) >> 6;
    const int row  = w * 16 + c16;

    // ---- first-layer B fragments from x (unscaled; 0.5 lives in A) ----
    const float4 xa = *reinterpret_cast<const float4*>(x + (size_t)row * 20 + 4 * h);
    const float4 xb = *reinterpret_cast<const float4*>(x + (size_t)row * 20 + 16);
    half4 Bk0 = mk_half4(pkrtz(xa.x, xa.y), pkrtz(xa.z, xa.w));
    unsigned iw0 = (h == 0) ? pkrtz(xb.x, xb.y) : ((h == 1) ? 0x00003C00u : 0u);
    unsigned iw1 = (h == 0) ? pkrtz(xb.z, xb.w) : 0u;
    half4 Bk1 = mk_half4(iw0, iw1);

    // ---- chunk staging: global->reg early, reg->LDS late ----
    float4 sreg[V4_PER_T];
    auto stage_load = [&](int c) {
        const float4* g = reinterpret_cast<const float4*>(wstream) + (size_t)c * CHUNK_V4;
#pragma unroll
        for (int j = 0; j < V4_PER_T; ++j) sreg[j] = g[j * 256 + tid];
    };
    auto stage_write = [&](int bufi) {
        float4* d = reinterpret_cast<float4*>(lds + bufi * CHUNK_BY);
#pragma unroll
        for (int j = 0; j < V4_PER_T; ++j) d[j * 256 + tid] = sreg[j];
    };

    const unsigned lbase = (unsigned)(uintptr_t)&lds[0];
    const unsigned b1A = lbase + lane * 16;          // b128 stream base
    const unsigned b2A = lbase + 1024 + lane * 8;    // b64 stream base
    const unsigned b1B = b1A + CHUNK_BY;
    const unsigned b2B = b2A + CHUNK_BY;

    stage_load(0); stage_write(0); __syncthreads();

    f32x2 q[4];

    const int NC = L / CL;   // 125
    for (int c = 0; c < NC; ++c) {
        if (c + 1 < NC) stage_load(c + 1);            // global prefetch (vmcnt)
        const unsigned cb1 = (c & 1) ? b1B : b1A;
        const unsigned cb2 = (c & 1) ? b2B : b2A;
        // ---- read the whole chunk's fragments into registers ----
        half8 fa0, fa1, fa2, fa3, fa4, fa5, fa6, fa7;
        half4 fb0, fb1, fb2, fb3, fb4, fb5, fb6, fb7;
        RD(0,     fa0, fb0)
        RD(1536,  fa1, fb1)
        RD(3072,  fa2, fb2)
        RD(4608,  fa3, fb3)
        RD(6144,  fa4, fb4)
        RD(7680,  fa5, fb5)
        RD(9216,  fa6, fb6)
        RD(10752, fa7, fb7)
        asm volatile("s_waitcnt lgkmcnt(0)");
        __builtin_amdgcn_sched_barrier(0);            // rule #18 fence (once)
        // ---- 8 layers, one straight-line scheduling region ----
        layer_step(fa0, fb0, Bk0, Bk1, q, h);
        layer_step(fa1, fb1, Bk0, Bk1, q, h);
        layer_step(fa2, fb2, Bk0, Bk1, q, h);
        layer_step(fa3, fb3, Bk0, Bk1, q, h);
        layer_step(fa4, fb4, Bk0, Bk1, q, h);
        layer_step(fa5, fb5, Bk0, Bk1, q, h);
        layer_step(fa6, fb6, Bk0, Bk1, q, h);
        layer_step(fa7, fb7, Bk0, Bk1, q, h);
        if (c + 1 < NC) {
            stage_write((c + 1) & 1);                 // loads long since landed
            __syncthreads();
        }
    }

    // ---- epilogue: lane (h,c16) holds neurons {4h+j} (q[0],q[1]) and
    // {16+4h+j} (q[2],q[3]; real only for h==0) ----
    const float4 woa = *reinterpret_cast<const float4*>(Wout + 4 * h);
    const float4 wob = *reinterpret_cast<const float4*>(Wout + 16);
    float part = q[0].x * woa.x + q[0].y * woa.y + q[1].x * woa.z + q[1].y * woa.w;
    const float m = (h == 0) ? 1.f : 0.f;
    part += m * (q[2].x * wob.x + q[2].y * wob.y + q[3].x * wob.z + q[3].y * wob.w);
    part += __shfl_xor(part, 16, 64);
    part += __shfl_xor(part, 32, 64);
    if (h == 0) out[row] = sigm(part + bout[0]);
}

extern "C" void kernel_launch(void* const* d_in, const int* in_sizes, int n_in,
                              void* d_out, int out_size, void* d_ws, size_t ws_size,
                              hipStream_t stream) {
    const float* x    = (const float*)d_in[0];
    const float* W    = (const float*)d_in[1];
    const float* b    = (const float*)d_in[2];
    const float* Wout = (const float*)d_in[3];
    const float* bout = (const float*)d_in[4];
    float* out = (float*)d_out;

    const int B = in_sizes[0] / 20;    // 16384
    const int L = in_sizes[1] / 400;   // 1000

    unsigned int* wstream = (unsigned int*)d_ws;   // L*1536 B = 1.54 MB

    prepack<<<L, 64, 0, stream>>>(W, b, wstream, L);

    const int grid = B / 64;           // 16 rows/wave, 4 waves/block
    mann_mfma<<<grid, 256, 0, stream>>>(x, wstream, Wout, bout, out, B, L);
}

// Round 18
// 253.647 us; speedup vs baseline: 1.0270x; 1.0270x over previous
//
#include <hip/hip_runtime.h>

#define LOG2E 1.44269504088896340736f

typedef __attribute__((ext_vector_type(8))) _Float16 half8;
typedef __attribute__((ext_vector_type(4))) _Float16 half4;
typedef __attribute__((ext_vector_type(4))) float f32x4;
typedef __attribute__((ext_vector_type(2))) float f32x2;
typedef __attribute__((ext_vector_type(2))) unsigned int uint2v;

constexpr int CL       = 8;               // layers per staged chunk (divides 1000)
constexpr int LAYER_BY = 1536;            // bytes/layer: 64 lanes x (16B A0 + 8B A1)
constexpr int CHUNK_BY = CL * LAYER_BY;   // 12288
constexpr int CHUNK_V4 = CHUNK_BY / 16;   // 768 float4
constexpr int V4_PER_T = CHUNK_V4 / 256;  // 3 per thread

// K=16 k-slot map (self-consistent between prepack/A and runtime/B):
//   chunk k0: slot(h,e) -> position 4h+e      (positions 0..15)
//   chunk k1: slot(h,e) -> position 16+4h+e   (16..19 real, 20 = bias, >20 pad)
// D layout (shape-determined, m89): col=lane&15, row=4*(lane>>4)+reg.

__device__ __forceinline__ unsigned short f16_rne(float f) {
    _Float16 h = (_Float16)f;   // RNE
    return __builtin_bit_cast(unsigned short, h);
}

// One block per layer; 64 threads (one per lane). Weights/bias PRE-SCALED by
// 0.5 (x = 0.5z feeds the Pade sigmoid directly), converted to f16.
__global__ void prepack(const float* __restrict__ W, const float* __restrict__ b,
                        unsigned int* __restrict__ wstream, int L)
{
    const int l    = blockIdx.x;
    const int lane = threadIdx.x;     // 0..63
    const int n    = lane & 15;       // tile0 neuron row
    const int h    = lane >> 4;

    unsigned short v[12];             // A0k0[4], A0k1[4], A1k1[4]
#pragma unroll
    for (int e = 0; e < 4; ++e) {
        v[e] = f16_rne(0.5f * W[(size_t)l * 400 + n * 20 + (4 * h + e)]);
        int p = 16 + 4 * h + e;
        float a = 0.f;
        if (p < 20)       a = 0.5f * W[(size_t)l * 400 + n * 20 + p];
        else if (p == 20) a = 0.5f * b[(size_t)l * 20 + n];
        v[4 + e] = f16_rne(a);
        float c = 0.f;
        int m1 = 16 + n;
        if (m1 < 20) {
            if (p < 20)       c = 0.5f * W[(size_t)l * 400 + m1 * 20 + p];
            else if (p == 20) c = 0.5f * b[(size_t)l * 20 + m1];
        }
        v[8 + e] = f16_rne(c);
    }
    unsigned w0 = (unsigned)v[0] | ((unsigned)v[1]  << 16);
    unsigned w1 = (unsigned)v[2] | ((unsigned)v[3]  << 16);
    unsigned w2 = (unsigned)v[4] | ((unsigned)v[5]  << 16);
    unsigned w3 = (unsigned)v[6] | ((unsigned)v[7]  << 16);
    unsigned w4 = (unsigned)v[8] | ((unsigned)v[9]  << 16);
    unsigned w5 = (unsigned)v[10]| ((unsigned)v[11] << 16);

    unsigned int* d0 = wstream + ((size_t)l * LAYER_BY + lane * 16) / 4;
    d0[0] = w0; d0[1] = w1; d0[2] = w2; d0[3] = w3;
    unsigned int* d1 = wstream + ((size_t)l * LAYER_BY + 1024 + lane * 8) / 4;
    d1[0] = w4; d1[1] = w5;
}

__device__ __forceinline__ unsigned pkrtz(float a, float b) {
    auto r = __builtin_amdgcn_cvt_pkrtz(a, b);   // __fp16 ext_vector(2)
    return __builtin_bit_cast(unsigned, r);
}
__device__ __forceinline__ half4 mk_half4(unsigned lo, unsigned hi) {
    uint2v u; u.x = lo; u.y = hi;
    return __builtin_bit_cast(half4, u);
}

__device__ __forceinline__ f32x2 make2(float v) { f32x2 r; r.x = v; r.y = v; return r; }

// sigmoid(z) with x = 0.5*z (scale folded into weights): 0.5 + x*N(u)/D(u).
// abs err <= ~2e-5 (|z|<=4), <= 1.2e-3 (z=8). Paired reciprocal: 1 rcp per 2
// divisions (rcp(dx*dy) * dy|dx) -> 4 rcp/layer instead of 8.
__device__ __forceinline__ f32x2 pade_sig(f32x2 x) {
    f32x2 u = x * x;
    f32x2 n = (u * make2(0.5f) + make2(52.5f)) * u + make2(472.5f);
    f32x2 d = (u * make2(15.0f) + make2(420.0f)) * u + make2(945.0f);
    float pr = __builtin_amdgcn_rcpf(d.x * d.y);
    f32x2 inv; inv.x = pr * d.y; inv.y = pr * d.x;
    return (x * n) * inv + make2(0.5f);
}

// full sigmoid for unscaled z (epilogue only, once)
__device__ __forceinline__ float sigm(float z) {
    return __builtin_amdgcn_rcpf(1.f + __builtin_amdgcn_exp2f(-LOG2E * z));
}

// Issue one layer's fragments: b128 (A0k0|A0k1) + b64 (A1k1). Volatile ->
// cannot be sunk. Immediate offsets walk the chunk's layers.
#define ISSUE_FRAG(base1, base2, OFF, A0, A1)                                   \
    asm volatile("ds_read_b128 %0, %1 offset:" #OFF : "=v"(A0) : "v"(base1));   \
    asm volatile("ds_read_b64 %0, %1 offset:" #OFF : "=v"(A1) : "v"(base2));

__device__ __forceinline__ void layer_step(const half8& a0, const half4& a1,
                                           half4& Bk0, half4& Bk1,
                                           f32x2 (&q)[4], int h) {
    const f32x4 z4 = {0.f, 0.f, 0.f, 0.f};
    const half4 A0k0 = __builtin_shufflevector(a0, a0, 0, 1, 2, 3);
    const half4 A0k1 = __builtin_shufflevector(a0, a0, 4, 5, 6, 7);
    // tile1 first: its D is on the loop-carried critical path (Bk1).
    f32x4 acc1 = __builtin_amdgcn_mfma_f32_16x16x16f16(a1,   Bk1, z4, 0, 0, 0);
    f32x4 acc0 = __builtin_amdgcn_mfma_f32_16x16x16f16(A0k0, Bk0, z4, 0, 0, 0);
    acc0       = __builtin_amdgcn_mfma_f32_16x16x16f16(A0k1, Bk1, acc0, 0, 0, 0);
    q[2].x = acc1[0]; q[2].y = acc1[1];
    q[3].x = acc1[2]; q[3].y = acc1[3];
    q[2] = pade_sig(q[2]); q[3] = pade_sig(q[3]);
    q[0].x = acc0[0]; q[0].y = acc0[1];
    q[1].x = acc0[2]; q[1].y = acc0[3];
    q[0] = pade_sig(q[0]); q[1] = pade_sig(q[1]);
    Bk0 = mk_half4(pkrtz(q[0].x, q[0].y), pkrtz(q[1].x, q[1].y));
    unsigned k1w0 = (h == 0) ? pkrtz(q[2].x, q[2].y)
                             : ((h == 1) ? 0x00003C00u : 0u);   // (1.0, 0) f16
    unsigned k1w1 = (h == 0) ? pkrtz(q[3].x, q[3].y) : 0u;
    Bk1 = mk_half4(k1w0, k1w1);
}

// 16 batch rows per wave; 1024 waves = 1/SIMD (structural). r9-proven LDS
// skeleton; K=16 f16 MFMAs (tile1 + C-chained tile0 pair).
__global__ __launch_bounds__(256, 1) void mann_mfma(
    const float* __restrict__ x, const unsigned int* __restrict__ wstream,
    const float* __restrict__ Wout, const float* __restrict__ bout,
    float* __restrict__ out, int B, int L)
{
    __shared__ unsigned char lds[2 * CHUNK_BY];   // 24 KiB double buffer

    const int tid  = threadIdx.x;
    const int lane = tid & 63;
    const int c16  = lane & 15;
    const int h    = lane >> 4;
    const int w    = (blockIdx.x * 256 + tid) >> 6;
    const int row  = w * 16 + c16;

    // ---- first-layer B fragments from x (unscaled; 0.5 lives in A) ----
    const float4 xa = *reinterpret_cast<const float4*>(x + (size_t)row * 20 + 4 * h);
    const float4 xb = *reinterpret_cast<const float4*>(x + (size_t)row * 20 + 16);
    half4 Bk0 = mk_half4(pkrtz(xa.x, xa.y), pkrtz(xa.z, xa.w));
    unsigned iw0 = (h == 0) ? pkrtz(xb.x, xb.y) : ((h == 1) ? 0x00003C00u : 0u);
    unsigned iw1 = (h == 0) ? pkrtz(xb.z, xb.w) : 0u;
    half4 Bk1 = mk_half4(iw0, iw1);

    // ---- chunk staging: global->reg early, reg->LDS late ----
    float4 sreg[V4_PER_T];
    auto stage_load = [&](int c) {
        const float4* g = reinterpret_cast<const float4*>(wstream) + (size_t)c * CHUNK_V4;
#pragma unroll
        for (int j = 0; j < V4_PER_T; ++j) sreg[j] = g[j * 256 + tid];
    };
    auto stage_write = [&](int bufi) {
        float4* d = reinterpret_cast<float4*>(lds + bufi * CHUNK_BY);
#pragma unroll
        for (int j = 0; j < V4_PER_T; ++j) d[j * 256 + tid] = sreg[j];
    };

    const unsigned lbase = (unsigned)(uintptr_t)&lds[0];
    const unsigned b1A = lbase + lane * 16;          // b128 stream base
    const unsigned b2A = lbase + 1024 + lane * 8;    // b64 stream base
    const unsigned b1B = b1A + CHUNK_BY;
    const unsigned b2B = b2A + CHUNK_BY;

    stage_load(0); stage_write(0); __syncthreads();

    // 4 named fragment buffers; buf[l & 3] holds layer l.
    half8 f0a, f1a, f2a, f3a;
    half4 f0b, f1b, f2b, f3b;

    ISSUE_FRAG(b1A, b2A, 0,    f0a, f0b);     // layer 0
    ISSUE_FRAG(b1A, b2A, 1536, f1a, f1b);     // layer 1

    f32x2 q[4];

    const int NC = L / CL;   // 125
    for (int c = 0; c < NC; ++c) {
        if (c + 1 < NC) stage_load(c + 1);            // global prefetch (vmcnt)
        const unsigned cb1 = (c & 1) ? b1B : b1A;
        const unsigned cb2 = (c & 1) ? b2B : b2A;
#pragma unroll
        for (int ll = 0; ll < CL; ++ll) {
            // 2 reads/layer; {ll, ll+1} outstanding -> drain oldest 2.
            if (ll == CL - 1) asm volatile("s_waitcnt lgkmcnt(0)");
            else              asm volatile("s_waitcnt lgkmcnt(2)");
            __builtin_amdgcn_sched_barrier(0);        // rule #18
            switch (ll + 2 < CL ? (ll + 2) : -1) {    // issue layer ll+2
                case 2: ISSUE_FRAG(cb1, cb2, 3072,  f2a, f2b); break;
                case 3: ISSUE_FRAG(cb1, cb2, 4608,  f3a, f3b); break;
                case 4: ISSUE_FRAG(cb1, cb2, 6144,  f0a, f0b); break;
                case 5: ISSUE_FRAG(cb1, cb2, 7680,  f1a, f1b); break;
                case 6: ISSUE_FRAG(cb1, cb2, 9216,  f2a, f2b); break;
                case 7: ISSUE_FRAG(cb1, cb2, 10752, f3a, f3b); break;
                default: break;
            }
            __builtin_amdgcn_sched_barrier(0);
            const int ci = ll & 3;
            if      (ci == 0) layer_step(f0a, f0b, Bk0, Bk1, q, h);
            else if (ci == 1) layer_step(f1a, f1b, Bk0, Bk1, q, h);
            else if (ci == 2) layer_step(f2a, f2b, Bk0, Bk1, q, h);
            else              layer_step(f3a, f3b, Bk0, Bk1, q, h);
        }
        if (c + 1 < NC) {
            stage_write((c + 1) & 1);                 // loads long since landed
            __syncthreads();
            const unsigned nb1 = ((c + 1) & 1) ? b1B : b1A;
            const unsigned nb2 = ((c + 1) & 1) ? b2B : b2A;
            ISSUE_FRAG(nb1, nb2, 0,    f0a, f0b);     // next chunk layer 0
            ISSUE_FRAG(nb1, nb2, 1536, f1a, f1b);     // next chunk layer 1
        }
    }

    // ---- epilogue: lane (h,c16) holds neurons {4h+j} (q[0],q[1]) and
    // {16+4h+j} (q[2],q[3]; real only for h==0) ----
    const float4 woa = *reinterpret_cast<const float4*>(Wout + 4 * h);
    const float4 wob = *reinterpret_cast<const float4*>(Wout + 16);
    float part = q[0].x * woa.x + q[0].y * woa.y + q[1].x * woa.z + q[1].y * woa.w;
    const float m = (h == 0) ? 1.f : 0.f;
    part += m * (q[2].x * wob.x + q[2].y * wob.y + q[3].x * wob.z + q[3].y * wob.w);
    part += __shfl_xor(part, 16, 64);
    part += __shfl_xor(part, 32, 64);
    if (h == 0) out[row] = sigm(part + bout[0]);
}

extern "C" void kernel_launch(void* const* d_in, const int* in_sizes, int n_in,
                              void* d_out, int out_size, void* d_ws, size_t ws_size,
                              hipStream_t stream) {
    const float* x    = (const float*)d_in[0];
    const float* W    = (const float*)d_in[1];
    const float* b    = (const float*)d_in[2];
    const float* Wout = (const float*)d_in[3];
    const float* bout = (const float*)d_in[4];
    float* out = (float*)d_out;

    const int B = in_sizes[0] / 20;    // 16384
    const int L = in_sizes[1] / 400;   // 1000

    unsigned int* wstream = (unsigned int*)d_ws;   // L*1536 B = 1.54 MB

    prepack<<<L, 64, 0, stream>>>(W, b, wstream, L);

    const int grid = B / 64;           // 16 rows/wave, 4 waves/block
    mann_mfma<<<grid, 256, 0, stream>>>(x, wstream, Wout, bout, out, B, L);
}